// Round 2
// baseline (2748.408 us; speedup 1.0000x reference)
//
#include <hip/hip_runtime.h>
#include <hip/hip_bf16.h>

#define NCOLS 10000
#define TK 32
#define EQ_CAP 2048

// monotone f32-bits -> u32 ordering key (ascending key == ascending float)
__device__ __forceinline__ unsigned int fkey(unsigned int u) {
    return (u & 0x80000000u) ? ~u : (u | 0x80000000u);
}

// One block per row: exact top-32 (value desc, lowest-index tie-break),
// output = the 32 winning indices sorted ascending.
__global__ __launch_bounds__(256) void topk_rows_f32(
        const float* __restrict__ sim, int* __restrict__ out_map) {
    const int row = blockIdx.x;
    const int tid = threadIdx.x;
    const uint4* rowv = (const uint4*)(sim + (size_t)row * NCOLS); // 2500 uint4, 16B aligned

    __shared__ unsigned int hist[256];
    __shared__ unsigned int s_b1, s_c1, s_T, s_ngt, s_m;
    __shared__ unsigned int cnt_gt, cnt_eq;
    __shared__ int gt_list[TK];
    __shared__ unsigned int eq_key[EQ_CAP];
    __shared__ int eq_idx[EQ_CAP];
    __shared__ int final_idx[TK];

    hist[tid] = 0;
    __syncthreads();
    // pass 1: histogram of key byte [31:24]
    for (int c = tid; c < NCOLS / 4; c += 256) {
        uint4 v = rowv[c];
        atomicAdd(&hist[fkey(v.x) >> 24], 1u);
        atomicAdd(&hist[fkey(v.y) >> 24], 1u);
        atomicAdd(&hist[fkey(v.z) >> 24], 1u);
        atomicAdd(&hist[fkey(v.w) >> 24], 1u);
    }
    __syncthreads();
    if (tid == 0) {
        unsigned cum = 0; unsigned b = 0;
        for (int i = 255; i >= 0; --i) {
            if (cum + hist[i] >= TK) { b = (unsigned)i; break; }
            cum += hist[i];
        }
        s_b1 = b; s_c1 = cum;
    }
    __syncthreads();
    const unsigned b1 = s_b1, c1 = s_c1;
    hist[tid] = 0;
    __syncthreads();
    // pass 2: histogram of key byte [23:16] within top byte == b1
    for (int c = tid; c < NCOLS / 4; c += 256) {
        uint4 v = rowv[c];
        unsigned k;
        k = fkey(v.x); if ((k >> 24) == b1) atomicAdd(&hist[(k >> 16) & 255u], 1u);
        k = fkey(v.y); if ((k >> 24) == b1) atomicAdd(&hist[(k >> 16) & 255u], 1u);
        k = fkey(v.z); if ((k >> 24) == b1) atomicAdd(&hist[(k >> 16) & 255u], 1u);
        k = fkey(v.w); if ((k >> 24) == b1) atomicAdd(&hist[(k >> 16) & 255u], 1u);
    }
    __syncthreads();
    if (tid == 0) {
        unsigned cum = c1; unsigned b = 0;
        for (int i = 255; i >= 0; --i) {
            if (cum + hist[i] >= TK) { b = (unsigned)i; break; }
            cum += hist[i];
        }
        s_T = (b1 << 8) | b;     // 16-bit prefix threshold
        s_ngt = cum;             // strictly greater prefixes (< 32)
        s_m = TK - cum;          // how many to take from the == bucket
        cnt_gt = 0; cnt_eq = 0;
    }
    __syncthreads();
    const unsigned T16 = s_T, ngt = s_ngt, m = s_m;
    // pass 3: collect winners and boundary-bucket candidates
    for (int c = tid; c < NCOLS / 4; c += 256) {
        uint4 v = rowv[c];
        unsigned ks[4] = { fkey(v.x), fkey(v.y), fkey(v.z), fkey(v.w) };
        #pragma unroll
        for (int i = 0; i < 4; ++i) {
            unsigned hi = ks[i] >> 16;
            int idx = c * 4 + i;
            if (hi > T16) {
                unsigned p = atomicAdd(&cnt_gt, 1u); gt_list[p] = idx;
            } else if (hi == T16) {
                unsigned p = atomicAdd(&cnt_eq, 1u);
                if (p < EQ_CAP) { eq_key[p] = ks[i]; eq_idx[p] = idx; }
            }
        }
    }
    __syncthreads();
    if (tid < (int)ngt) final_idx[tid] = gt_list[tid];
    const int E = (int)min(cnt_eq, (unsigned)EQ_CAP);
    // exact select of m best among boundary bucket: (full key desc, index asc)
    for (int i = tid; i < E; i += 256) {
        unsigned ki = eq_key[i]; int vi = eq_idx[i];
        int r = 0;
        for (int j = 0; j < E; ++j) {
            unsigned kj = eq_key[j];
            r += (kj > ki) || (kj == ki && eq_idx[j] < vi);
        }
        if (r < (int)m) final_idx[ngt + r] = vi;
    }
    __syncthreads();
    if (tid < TK) {
        int v = final_idx[tid];
        int r = 0;
        #pragma unroll
        for (int j = 0; j < TK; ++j) r += (final_idx[j] < v);
        out_map[(size_t)row * TK + r] = v;   // sorted ascending
    }
}

// One block (256 threads) per sample.
__global__ __launch_bounds__(256) void sample_f32(
        const int* __restrict__ data,
        const float* __restrict__ user_emb,
        const float* __restrict__ service_emb,
        const int* __restrict__ u_map, const int* __restrict__ s_map,
        const float* __restrict__ cnn_w, const float* __restrict__ cnn_b,
        const float* __restrict__ scnn_w, const float* __restrict__ scnn_b,
        const float* __restrict__ wi, const float* __restrict__ bi,
        const float* __restrict__ wf, const float* __restrict__ bfb,
        const float* __restrict__ fc_w, const float* __restrict__ fc_b,
        float* __restrict__ out) {
    const int s = blockIdx.x;
    const int tid = threadIdx.x;

    __shared__ float u_nb[32][128];
    __shared__ float s_nb[32][128];
    __shared__ float feats[4][128];      // a, b, c, d
    __shared__ float gmat[2][6][128];    // [0]=wf result, [1]=wi result
    __shared__ float tempt[6][128];
    __shared__ float cw[224], sw[224];
    __shared__ int umr[32], smr[32];
    __shared__ float sumsq_s[6];
    __shared__ int order[4];
    __shared__ float partials[4][64];

    const int uid = data[s * 3 + 1];
    const int sid = data[s * 3 + 2];

    if (tid < 32) {
        umr[tid] = u_map[(size_t)uid * 32 + tid];
        smr[tid] = s_map[(size_t)sid * 32 + tid];
    }
    if (tid < 128) feats[0][tid] = user_emb[(size_t)uid * 128 + tid];
    else { int h = tid - 128; feats[1][h] = service_emb[(size_t)sid * 128 + h]; }
    if (tid < 224) { cw[tid] = cnn_w[tid]; sw[tid] = scnn_w[tid]; }
    __syncthreads();

    // gather neighbor embeddings (float4 loads, 32 rows x 32 chunks)
    for (int e = tid; e < 32 * 32; e += 256) {
        int k = e >> 5, c = e & 31;
        float4 vu = ((const float4*)(user_emb + (size_t)umr[k] * 128))[c];
        float4 vs = ((const float4*)(service_emb + (size_t)smr[k] * 128))[c];
        ((float4*)&u_nb[k][0])[c] = vu;
        ((float4*)&s_nb[k][0])[c] = vs;
    }
    __syncthreads();

    // conv: threads 0-127 -> c, 128-255 -> d
    {
        const int h = tid & 127;
        const bool isU = tid < 128;
        const float (*NB)[128] = isU ? u_nb : s_nb;
        const float* W = isU ? cw : sw;
        float acc = isU ? cnn_b[0] : scnn_b[0];
        for (int k = 0; k < 32; ++k) {
            #pragma unroll
            for (int t = 0; t < 7; ++t) {
                int hh = h + t - 3;
                if (hh >= 0 && hh < 128) acc += NB[k][hh] * W[k * 7 + t];
            }
        }
        if (isU) feats[2][h] = acc; else feats[3][h] = acc;
    }
    __syncthreads();

    // two 6x128 @ 128x128 matmuls (wf and wi)
    for (int o = tid; o < 1536; o += 256) {
        int m = o / 768;
        int rem = o - m * 768;
        int p = rem >> 7, j = rem & 127;
        int pi = (0x211000u >> (4 * p)) & 15;   // ii = 0,0,0,1,1,2
        int pj = (0x332321u >> (4 * p)) & 15;   // jj = 1,2,3,2,3,3
        const float* A = feats[pi];
        const float* Bv = feats[pj];
        const float4* Wv = (const float4*)((m ? wi : wf) + (size_t)j * 128);
        float acc = (m ? bi : bfb)[j];
        for (int c = 0; c < 32; ++c) {
            float4 w = Wv[c];
            int h0 = c * 4;
            acc += (A[h0 + 0] + Bv[h0 + 0]) * w.x;
            acc += (A[h0 + 1] + Bv[h0 + 1]) * w.y;
            acc += (A[h0 + 2] + Bv[h0 + 2]) * w.z;
            acc += (A[h0 + 3] + Bv[h0 + 3]) * w.w;
        }
        gmat[m][p][j] = acc;
    }
    __syncthreads();

    // gate + relu
    for (int o = tid; o < 768; o += 256) {
        int p = o >> 7, j = o & 127;
        int pi = (0x211000u >> (4 * p)) & 15;
        int pj = (0x332321u >> (4 * p)) & 15;
        float sp = feats[pi][j] + feats[pj][j];
        float f = 1.0f / (1.0f + expf(-gmat[0][p][j]));
        float v = f * gmat[1][p][j] + (1.0f - f) * sp;
        tempt[p][j] = v > 0.0f ? v : 0.0f;
    }
    __syncthreads();

    if (tid < 6) {
        float ss = 0.0f;
        for (int j = 0; j < 128; ++j) { float v = tempt[tid][j]; ss += v * v; }
        sumsq_s[tid] = ss;
    }
    __syncthreads();
    if (tid == 0) {
        unsigned used = 0;
        for (int r = 0; r < 4; ++r) {
            int best = -1; float bv = 0.0f;
            for (int p = 0; p < 6; ++p) {
                if (used & (1u << p)) continue;
                if (best < 0 || sumsq_s[p] > bv) { best = p; bv = sumsq_s[p]; }
            }
            used |= 1u << best;
            order[r] = best;   // descending norm, lowest index on ties
        }
    }
    __syncthreads();

    // fc: out[o] = sum_q x[q]*fc_w[o][q] + fc_b[o], x = concat of 4 selected rows
    {
        const int o = tid & 63, g = tid >> 6;
        const int p = order[g];
        const float4* Wv = (const float4*)(fc_w + (size_t)o * 512 + g * 128);
        float acc = 0.0f;
        for (int c = 0; c < 32; ++c) {
            float4 w = Wv[c];
            int j0 = c * 4;
            acc += tempt[p][j0 + 0] * w.x;
            acc += tempt[p][j0 + 1] * w.y;
            acc += tempt[p][j0 + 2] * w.z;
            acc += tempt[p][j0 + 3] * w.w;
        }
        partials[g][o] = acc;
    }
    __syncthreads();
    if (tid < 64) {
        float v = partials[0][tid] + partials[1][tid] + partials[2][tid] + partials[3][tid]
                + fc_b[tid];
        out[(size_t)s * 64 + tid] = v;
    }
}

extern "C" void kernel_launch(void* const* d_in, const int* in_sizes, int n_in,
                              void* d_out, int out_size, void* d_ws, size_t ws_size,
                              hipStream_t stream) {
    const int*   data        = (const int*)d_in[0];
    const float* user_sim    = (const float*)d_in[1];
    const float* service_sim = (const float*)d_in[2];
    const float* user_emb    = (const float*)d_in[3];
    const float* service_emb = (const float*)d_in[4];
    const float* cnn_w       = (const float*)d_in[5];
    const float* cnn_b       = (const float*)d_in[6];
    const float* scnn_w      = (const float*)d_in[7];
    const float* scnn_b      = (const float*)d_in[8];
    const float* wi          = (const float*)d_in[9];
    const float* bi          = (const float*)d_in[10];
    const float* wf          = (const float*)d_in[11];
    const float* bfb         = (const float*)d_in[12];
    const float* fc_w        = (const float*)d_in[13];
    const float* fc_b        = (const float*)d_in[14];

    const int U_n = in_sizes[3] / 128;   // 10000
    const int S_n = in_sizes[4] / 128;   // 10000
    const int B   = in_sizes[0] / 3;     // 16384

    int* u_map_d = (int*)d_ws;
    int* s_map_d = u_map_d + (size_t)U_n * 32;

    topk_rows_f32<<<U_n, 256, 0, stream>>>(user_sim, u_map_d);
    topk_rows_f32<<<S_n, 256, 0, stream>>>(service_sim, s_map_d);
    sample_f32<<<B, 256, 0, stream>>>(data, user_emb, service_emb,
                                      u_map_d, s_map_d,
                                      cnn_w, cnn_b, scnn_w, scnn_b,
                                      wi, bi, wf, bfb, fc_w, fc_b,
                                      (float*)d_out);
}